// Round 2
// baseline (1086.540 us; speedup 1.0000x reference)
//
#include <hip/hip_runtime.h>

// MultiHeadTEAttention: M=8, NQ=NKV=1024, DX=512, H=8, HD=64, KHID=16, DT=2
// Inputs/outputs are f32 on device (values bf16-rounded by harness).
// Workspace intermediates Q/K/V/O stored bf16 (within 2% threshold).

typedef unsigned short u16;
typedef unsigned int   u32;

#define Mb   8
#define NQ   1024
#define NKV  1024
#define DX   512
#define Hh   8
#define HD   64
#define INNER 512
#define KHID 16
#define SCALE 0.125f

__device__ __forceinline__ float bf_lo(u32 u) {
    union { u32 u; float f; } v; v.u = u << 16; return v.f;
}
__device__ __forceinline__ float bf_hi(u32 u) {
    union { u32 u; float f; } v; v.u = u & 0xffff0000u; return v.f;
}
__device__ __forceinline__ u16 f2bf(float f) {
    union { float f; u32 u; } v; v.f = f;
    u32 r = v.u + 0x7fffu + ((v.u >> 16) & 1u);   // RNE
    return (u16)(r >> 16);
}

// ---------------------------------------------------------------------------
// C = A @ B (+bias). A:[8192 x 512] (f32 or bf16), B:[512 x 512] f32,
// C (bf16 or f32). tile 64x64, 256 threads, 4x4/thread, K-chunk 16, f32 accum.
// ---------------------------------------------------------------------------
template<int A_BF16, int OUT_BF16>
__global__ __launch_bounds__(256) void gemm512(
    const void* __restrict__ Av, const float* __restrict__ B,
    const float* __restrict__ bias, void* __restrict__ Cv, int hasBias)
{
    __shared__ float As[16][64];
    __shared__ float Bs[16][64];

    const int tid = threadIdx.x;
    const int tx = tid & 15, ty = tid >> 4;
    const int m0 = blockIdx.y * 64, n0 = blockIdx.x * 64;

    float acc[4][4] = {};

    for (int kc = 0; kc < 512; kc += 16) {
        // stage A tile (64 rows x 16 k), 4 elems/thread
        {
            const int row = tid >> 2, kk = (tid & 3) * 4;
            if (A_BF16) {
                const u16* ap = (const u16*)Av + (size_t)(m0 + row) * 512 + kc + kk;
                uint2 u = *(const uint2*)ap;
                As[kk + 0][row] = bf_lo(u.x); As[kk + 1][row] = bf_hi(u.x);
                As[kk + 2][row] = bf_lo(u.y); As[kk + 3][row] = bf_hi(u.y);
            } else {
                const float* ap = (const float*)Av + (size_t)(m0 + row) * 512 + kc + kk;
                float4 a = *(const float4*)ap;
                As[kk + 0][row] = a.x; As[kk + 1][row] = a.y;
                As[kk + 2][row] = a.z; As[kk + 3][row] = a.w;
            }
        }
        // stage B tile (16 k x 64 cols)
        {
            const int krow = tid >> 4, c4 = (tid & 15) * 4;
            const float* bp = B + (size_t)(kc + krow) * 512 + n0 + c4;
            *(float4*)&Bs[krow][c4] = *(const float4*)bp;
        }
        __syncthreads();
        #pragma unroll
        for (int kk = 0; kk < 16; ++kk) {
            float4 a4 = *(const float4*)&As[kk][ty * 4];
            float4 b4 = *(const float4*)&Bs[kk][tx * 4];
            float a[4] = {a4.x, a4.y, a4.z, a4.w};
            float b[4] = {b4.x, b4.y, b4.z, b4.w};
            #pragma unroll
            for (int i = 0; i < 4; ++i)
                #pragma unroll
                for (int j = 0; j < 4; ++j)
                    acc[i][j] = fmaf(a[i], b[j], acc[i][j]);
        }
        __syncthreads();
    }

    float bf[4] = {0.f, 0.f, 0.f, 0.f};
    if (hasBias) {
        #pragma unroll
        for (int j = 0; j < 4; ++j) bf[j] = bias[n0 + tx * 4 + j];
    }
    #pragma unroll
    for (int i = 0; i < 4; ++i) {
        const size_t row = m0 + ty * 4 + i;
        float r[4];
        #pragma unroll
        for (int j = 0; j < 4; ++j) r[j] = acc[i][j] + bf[j];
        if (OUT_BF16) {
            uint2 pk;
            pk.x = (u32)f2bf(r[0]) | ((u32)f2bf(r[1]) << 16);
            pk.y = (u32)f2bf(r[2]) | ((u32)f2bf(r[3]) << 16);
            *(uint2*)((u16*)Cv + row * 512 + n0 + tx * 4) = pk;
        } else {
            float4 pk = make_float4(r[0], r[1], r[2], r[3]);
            *(float4*)((float*)Cv + row * 512 + n0 + tx * 4) = pk;
        }
    }
}

// ---------------------------------------------------------------------------
// Fused attention: block = (m, 16-query tile), all 8 heads, online softmax
// over NKV in tiles of TK=8. Pairwise MLP bias computed once per (q,k) pair.
// Q/K/V are bf16 (workspace); tq/tk and MLP weights are f32.
// ---------------------------------------------------------------------------
#define TQ 16
#define TK 8

__global__ __launch_bounds__(256) void attn_kernel(
    const u16* __restrict__ Qw, const u16* __restrict__ Kw,
    const u16* __restrict__ Vw,
    const float* __restrict__ tq, const float* __restrict__ tk,
    const float* __restrict__ kw1, const float* __restrict__ kb1,
    const float* __restrict__ kw2, const float* __restrict__ kb2,
    u16* __restrict__ Ow)
{
    __shared__ u16   sQ[TQ][520];        // bf16 Q tile, +8 pad
    __shared__ float sK[TK][516];        // f32 K tile
    __shared__ float sV[TK][516];        // f32 V tile
    __shared__ float sS[Hh * TK * TQ];   // [h][k][q] scores -> P
    __shared__ float sM[Hh * TQ], sL[Hh * TQ], sAl[Hh * TQ];
    __shared__ float stq[TQ * 2], stk[TK * 2];
    __shared__ float skw1[32], skb1[16], skw2[128], skb2[8];

    const int tid = threadIdx.x;
    const int m  = blockIdx.x >> 6;          // 64 q-tiles per batch
    const int q0 = (blockIdx.x & 63) * TQ;

    // ---- one-time init ----
    if (tid < 32)       skw1[tid]       = kw1[tid];
    else if (tid < 48)  skb1[tid - 32]  = kb1[tid - 32];
    else if (tid < 176) skw2[tid - 48]  = kw2[tid - 48];
    else if (tid < 184) skb2[tid - 176] = kb2[tid - 176];
    if (tid < TQ * 2) stq[tid] = tq[(size_t)(m * NQ + q0) * 2 + tid];
    if (tid < Hh * TQ) { sM[tid] = -1e30f; sL[tid] = 0.f; }
    {
        const u32* gQ = (const u32*)(Qw + (size_t)(m * NQ + q0) * 512);
        #pragma unroll
        for (int i = 0; i < 16; ++i) {           // 16*512 bf16 = 4096 u32
            int ui = tid + i * 256;
            int row = ui >> 8, col = ui & 255;
            ((u32*)&sQ[row][0])[col] = gQ[ui];
        }
    }

    // per-thread O accumulator: q = tid&15, s = tid>>4 -> head h=s>>1, half dh=s&1
    const int oq = tid & 15, os = tid >> 4;
    const int oh = os >> 1, odh = os & 1;
    const int dbase = oh * 64 + odh * 32;
    float o[32];
    #pragma unroll
    for (int d = 0; d < 32; ++d) o[d] = 0.f;

    for (int kt = 0; kt < NKV / TK; ++kt) {
        const int k0 = kt * TK;
        __syncthreads();   // previous O-update done / init done

        // ---- stage K,V (bf16 -> f32) ----
        {
            const u32* gK = (const u32*)(Kw + (size_t)(m * NKV + k0) * 512);
            const u32* gV = (const u32*)(Vw + (size_t)(m * NKV + k0) * 512);
            #pragma unroll
            for (int i = 0; i < 8; ++i) {        // 8*512 bf16 = 2048 u32
                int ui = tid + i * 256;
                int row = ui >> 8, col = (ui & 255) * 2;
                u32 uk = gK[ui], uv = gV[ui];
                sK[row][col] = bf_lo(uk); sK[row][col + 1] = bf_hi(uk);
                sV[row][col] = bf_lo(uv); sV[row][col + 1] = bf_hi(uv);
            }
            if (tid < TK * 2) stk[tid] = tk[(size_t)(m * NKV + k0) * 2 + tid];
        }
        __syncthreads();

        // ---- scores: thread = (q, k, head-group of 4) ----
        {
            const int q = tid & 15;
            const int k = (tid >> 4) & 7;
            const int hg = tid >> 7;             // 0/1 -> heads 0-3 / 4-7
            const float d0 = stq[q * 2 + 0] - stk[k * 2 + 0];
            const float d1 = stq[q * 2 + 1] - stk[k * 2 + 1];
            float hid[16];
            #pragma unroll
            for (int c = 0; c < 16; ++c) {
                float v = fmaf(d0, skw1[c], fmaf(d1, skw1[16 + c], skb1[c]));
                hid[c] = v > 0.f ? v : 0.f;
            }
            const u32* qrow = (const u32*)&sQ[q][0];
            #pragma unroll
            for (int hh = 0; hh < 4; ++hh) {
                const int h = hg * 4 + hh;
                float b = skb2[h];
                #pragma unroll
                for (int c = 0; c < 16; ++c) b = fmaf(hid[c], skw2[c * 8 + h], b);
                float acc = 0.f;
                const float* krow = &sK[k][h * 64];
                const u32*   qh   = qrow + h * 32;
                #pragma unroll
                for (int dd = 0; dd < 16; ++dd) {
                    float4 kv = *(const float4*)&krow[dd * 4];
                    uint2  qu = *(const uint2*)&qh[dd * 2];
                    acc = fmaf(bf_lo(qu.x), kv.x, acc);
                    acc = fmaf(bf_hi(qu.x), kv.y, acc);
                    acc = fmaf(bf_lo(qu.y), kv.z, acc);
                    acc = fmaf(bf_hi(qu.y), kv.w, acc);
                }
                sS[(h * TK + k) * TQ + q] = fmaf(acc, SCALE, b);
            }
        }
        __syncthreads();

        // ---- online softmax update (one thread per (h,q) row) ----
        if (tid < Hh * TQ) {
            const int h = tid >> 4, q = tid & 15;
            float mold = sM[tid];
            float mmax = mold;
            #pragma unroll
            for (int k = 0; k < TK; ++k)
                mmax = fmaxf(mmax, sS[(h * TK + k) * TQ + q]);
            float alpha = __expf(mold - mmax);
            float l = sL[tid] * alpha;
            #pragma unroll
            for (int k = 0; k < TK; ++k) {
                float p = __expf(sS[(h * TK + k) * TQ + q] - mmax);
                sS[(h * TK + k) * TQ + q] = p;
                l += p;
            }
            sM[tid] = mmax; sL[tid] = l; sAl[tid] = alpha;
        }
        __syncthreads();

        // ---- O update: thread owns (q, h, 32 dims) ----
        {
            const float alpha = sAl[oh * TQ + oq];
            #pragma unroll
            for (int d = 0; d < 32; ++d) o[d] *= alpha;
            #pragma unroll
            for (int k = 0; k < TK; ++k) {
                const float p = sS[(oh * TK + k) * TQ + oq];
                const float* vrow = &sV[k][dbase];
                #pragma unroll
                for (int dd = 0; dd < 8; ++dd) {
                    float4 vv = *(const float4*)&vrow[dd * 4];
                    o[dd * 4 + 0] = fmaf(p, vv.x, o[dd * 4 + 0]);
                    o[dd * 4 + 1] = fmaf(p, vv.y, o[dd * 4 + 1]);
                    o[dd * 4 + 2] = fmaf(p, vv.z, o[dd * 4 + 2]);
                    o[dd * 4 + 3] = fmaf(p, vv.w, o[dd * 4 + 3]);
                }
            }
        }
    }

    // ---- finalize: divide by l, write bf16 ----
    {
        const float inv = 1.f / sL[oh * TQ + oq];
        u32* og = (u32*)(Ow + (size_t)(m * NQ + q0 + oq) * 512 + dbase);
        #pragma unroll
        for (int i = 0; i < 16; ++i) {
            u32 lo = f2bf(o[2 * i] * inv);
            u32 hi = f2bf(o[2 * i + 1] * inv);
            og[i] = lo | (hi << 16);
        }
    }
}

// ---------------------------------------------------------------------------
extern "C" void kernel_launch(void* const* d_in, const int* in_sizes, int n_in,
                              void* d_out, int out_size, void* d_ws, size_t ws_size,
                              hipStream_t stream) {
    const float* xq    = (const float*)d_in[0];
    const float* xk    = (const float*)d_in[1];
    const float* xv    = (const float*)d_in[2];
    const float* tq    = (const float*)d_in[3];
    const float* tk    = (const float*)d_in[4];
    const float* w_q   = (const float*)d_in[5];
    const float* w_k   = (const float*)d_in[6];
    const float* w_v   = (const float*)d_in[7];
    const float* w_out = (const float*)d_in[8];
    const float* b_out = (const float*)d_in[9];
    const float* kw1   = (const float*)d_in[10];
    const float* kb1   = (const float*)d_in[11];
    const float* kw2   = (const float*)d_in[12];
    const float* kb2   = (const float*)d_in[13];

    const size_t nTok = (size_t)Mb * NQ * INNER;   // 4,194,304 elems
    u16* Q = (u16*)d_ws;
    u16* K = Q + nTok;
    u16* V = K + nTok;
    u16* O = V + nTok;

    dim3 gg(512 / 64, (Mb * NQ) / 64);   // (8, 128)
    gemm512<0,1><<<gg, 256, 0, stream>>>(xq, w_q, nullptr, Q, 0);
    gemm512<0,1><<<gg, 256, 0, stream>>>(xk, w_k, nullptr, K, 0);
    gemm512<0,1><<<gg, 256, 0, stream>>>(xv, w_v, nullptr, V, 0);

    attn_kernel<<<(Mb * NQ) / TQ, 256, 0, stream>>>(Q, K, V, tq, tk,
                                                    kw1, kb1, kw2, kb2, O);

    gemm512<1,0><<<gg, 256, 0, stream>>>(O, w_out, b_out, d_out, 1);
}

// Round 3
// 307.344 us; speedup vs baseline: 3.5353x; 3.5353x over previous
//
#include <hip/hip_runtime.h>

// MultiHeadTEAttention MFMA version.
// M=8, NQ=NKV=1024, DX=512, H=8, HD=64, KHID=16, DT=2. f32 in/out, bf16 compute.

typedef unsigned short u16;
typedef unsigned int   u32;
typedef short bf8 __attribute__((ext_vector_type(8)));   // 8 bf16 = 4 VGPR
typedef float f4  __attribute__((ext_vector_type(4)));

#define Mb 8
#define SCALE 0.125f

__device__ __forceinline__ u16 f2bf(float f) {
    union { float f; u32 u; } v; v.f = f;
    u32 r = v.u + 0x7fffu + ((v.u >> 16) & 1u);   // RNE
    return (u16)(r >> 16);
}
__device__ __forceinline__ u32 pk2(float a, float b) {
    return (u32)f2bf(a) | ((u32)f2bf(b) << 16);
}

// ===========================================================================
// GEMM: C = A[8192x512] @ W[512x512] (+bias). bf16 MFMA, f32 accumulate.
// LDS layout [seg(4)][row(128)][8 bf16]; seg = k-octet of BK=32.
// trans=0: D rows = W-cols (n)  -> store C[tok][n] (packed along n)
// trans=1: D rows = tokens      -> store Vt[mb][n][tokb] (packed along tok)
// ===========================================================================
struct GArgs {
    const void*  A[3];
    const float* W[3];
    void*        C[3];
    const float* bias;
    int          modeT[3];
    int          outf32;
    int          abf16;
};

__global__ __launch_bounds__(256) void gemm_mfma(GArgs g) {
    __shared__ u16 Xs[4][128][8];
    __shared__ u16 Ws[4][128][8];

    const int z   = blockIdx.z;
    const int tid = threadIdx.x;
    const int w = tid >> 6, lane = tid & 63, quad = lane >> 4, l16 = lane & 15;
    const int wm = w >> 1, wn = w & 1;
    const int n0 = blockIdx.x * 128, t0 = blockIdx.y * 128;
    const int trans = g.modeT[z];

    f4 acc[4][4];
    #pragma unroll
    for (int i = 0; i < 4; ++i)
        #pragma unroll
        for (int j = 0; j < 4; ++j) acc[i][j] = (f4)0.f;

    const float* Wp = g.W[z];

    for (int kc = 0; kc < 512; kc += 32) {
        __syncthreads();
        // ---- stage A tile (128 tok x 32 k) ----
        {
            const int row = tid >> 1, half = tid & 1;
            if (g.abf16) {
                const u16* ap = (const u16*)g.A[z] + (size_t)(t0 + row) * 512 + kc + half * 16;
                uint4 v0 = *(const uint4*)ap;
                uint4 v1 = *(const uint4*)(ap + 8);
                *(uint4*)&Xs[half * 2][row][0]     = v0;
                *(uint4*)&Xs[half * 2 + 1][row][0] = v1;
            } else {
                const float* ap = (const float*)g.A[z] + (size_t)(t0 + row) * 512 + kc + half * 16;
                float4 a0 = *(const float4*)(ap + 0);
                float4 a1 = *(const float4*)(ap + 4);
                float4 a2 = *(const float4*)(ap + 8);
                float4 a3 = *(const float4*)(ap + 12);
                uint4 v0, v1;
                v0.x = pk2(a0.x, a0.y); v0.y = pk2(a0.z, a0.w);
                v0.z = pk2(a1.x, a1.y); v0.w = pk2(a1.z, a1.w);
                v1.x = pk2(a2.x, a2.y); v1.y = pk2(a2.z, a2.w);
                v1.z = pk2(a3.x, a3.y); v1.w = pk2(a3.z, a3.w);
                *(uint4*)&Xs[half * 2][row][0]     = v0;
                *(uint4*)&Xs[half * 2 + 1][row][0] = v1;
            }
        }
        // ---- stage W tile transposed: Ws[n][k] = W[k][n0+n] ----
        #pragma unroll
        for (int i = 0; i < 4; ++i) {
            const int s = tid + i * 256;
            const int n = s & 127, kg = s >> 7;          // kg in [0,8): group of 4 k
            const int kb = kc + kg * 4;
            float v0 = Wp[(size_t)(kb + 0) * 512 + n0 + n];
            float v1 = Wp[(size_t)(kb + 1) * 512 + n0 + n];
            float v2 = Wp[(size_t)(kb + 2) * 512 + n0 + n];
            float v3 = Wp[(size_t)(kb + 3) * 512 + n0 + n];
            uint2 pw; pw.x = pk2(v0, v1); pw.y = pk2(v2, v3);
            *(uint2*)&Ws[kg >> 1][n][(kg & 1) * 4] = pw;
        }
        __syncthreads();

        // ---- MFMA: aop rows from (trans ? Xs : Ws), bop rows from the other
        const u16 (*Aop)[128][8] = trans ? Xs : Ws;
        const u16 (*Bop)[128][8] = trans ? Ws : Xs;
        const int arow = (trans ? wm : wn) * 64;
        const int brow = (trans ? wn : wm) * 64;
        bf8 af[4], bf[4];
        #pragma unroll
        for (int i = 0; i < 4; ++i) af[i] = *(const bf8*)&Aop[quad][arow + i * 16 + l16][0];
        #pragma unroll
        for (int j = 0; j < 4; ++j) bf[j] = *(const bf8*)&Bop[quad][brow + j * 16 + l16][0];
        #pragma unroll
        for (int i = 0; i < 4; ++i)
            #pragma unroll
            for (int j = 0; j < 4; ++j)
                acc[i][j] = __builtin_amdgcn_mfma_f32_16x16x32_bf16(af[i], bf[j], acc[i][j], 0, 0, 0);
    }

    // ---- epilogue ----
    if (g.outf32) {
        // D[n][tok] f32 + bias -> C[tok][n]
        float* Co = (float*)g.C[z];
        #pragma unroll
        for (int i = 0; i < 4; ++i) {
            const int nb = n0 + wn * 64 + i * 16 + quad * 4;
            float4 bv = *(const float4*)&g.bias[nb];
            #pragma unroll
            for (int j = 0; j < 4; ++j) {
                const int tok = t0 + wm * 64 + j * 16 + l16;
                float4 st;
                st.x = acc[i][j][0] + bv.x; st.y = acc[i][j][1] + bv.y;
                st.z = acc[i][j][2] + bv.z; st.w = acc[i][j][3] + bv.w;
                *(float4*)&Co[(size_t)tok * 512 + nb] = st;
            }
        }
    } else if (!trans) {
        // D[n][tok] -> bf16 C[tok][n]
        u16* C = (u16*)g.C[z];
        #pragma unroll
        for (int i = 0; i < 4; ++i) {
            const int nb = n0 + wn * 64 + i * 16 + quad * 4;
            #pragma unroll
            for (int j = 0; j < 4; ++j) {
                const int tok = t0 + wm * 64 + j * 16 + l16;
                uint2 pw;
                pw.x = pk2(acc[i][j][0], acc[i][j][1]);
                pw.y = pk2(acc[i][j][2], acc[i][j][3]);
                *(uint2*)&C[(size_t)tok * 512 + nb] = pw;
            }
        }
    } else {
        // D[tok][n] -> bf16 Vt[mb][n][tokb]
        u16* Vt = (u16*)g.C[z];
        #pragma unroll
        for (int i = 0; i < 4; ++i) {
            const int tokb = t0 + wm * 64 + i * 16 + quad * 4;
            const int mb = tokb >> 10, tb = tokb & 1023;
            #pragma unroll
            for (int j = 0; j < 4; ++j) {
                const int n = n0 + wn * 64 + j * 16 + l16;
                uint2 pw;
                pw.x = pk2(acc[i][j][0], acc[i][j][1]);
                pw.y = pk2(acc[i][j][2], acc[i][j][3]);
                *(uint2*)&Vt[(size_t)mb * 524288 + (size_t)n * 1024 + tb] = pw;
            }
        }
    }
}

// ===========================================================================
// Fused flash attention (MFMA). Block = (qt, h, m): 64 queries, one head.
// Computes S^T = K·Q^T (D rows = keys, cols = q), online softmax per q-col,
// O^T = Vt·P^T. P round-trips through wave-private LDS.
// ===========================================================================
__global__ __launch_bounds__(256) void attn_mfma(
    const u16* __restrict__ Q, const u16* __restrict__ K,
    const u16* __restrict__ Vt,
    const float* __restrict__ tqp, const float* __restrict__ tkp,
    const float* __restrict__ kw1, const float* __restrict__ kb1,
    const float* __restrict__ kw2,
    u16* __restrict__ O)
{
    __shared__ u16   sK[8][64][8];    // [d-octet][key][8 bf16]
    __shared__ u16   sV[8][64][8];    // [key-octet][d][8 bf16]
    __shared__ float sv[16][68];      // [c][key] : tk @ kw1
    __shared__ u16   sP[4][16][68];   // per-wave P [q][key], +4 pad

    const int tid = threadIdx.x;
    const int w = tid >> 6, lane = tid & 63, quad = lane >> 4, l16 = lane & 15;
    const int qt = blockIdx.x, h = blockIdx.y, m = blockIdx.z;
    const int q0 = qt * 64;
    const size_t qtok = (size_t)m * 1024 + q0 + w * 16 + l16;

    // Q fragments (d = kc*32 + quad*8 + j), q = l16
    bf8 qf[2];
    {
        const u16* qp = Q + qtok * 512 + h * 64 + quad * 8;
        qf[0] = *(const bf8*)qp;
        qf[1] = *(const bf8*)(qp + 32);
    }
    // u_q[c] = tq@kw1 + kb1 ; w2h[c] = kw2[c][h]  (kb2 softmax-invariant)
    float u[16], w2h[16];
    {
        const float t0v = tqp[qtok * 2], t1v = tqp[qtok * 2 + 1];
        #pragma unroll
        for (int c = 0; c < 16; ++c) {
            u[c] = fmaf(t0v, kw1[c], fmaf(t1v, kw1[16 + c], kb1[c]));
            w2h[c] = kw2[c * 8 + h];
        }
    }

    float mrun = -1e30f, lrun = 0.f;
    f4 o[4];
    #pragma unroll
    for (int d = 0; d < 4; ++d) o[d] = (f4)0.f;

    for (int kt = 0; kt < 16; ++kt) {
        const int k0 = kt * 64;
        __syncthreads();
        // ---- stage K tile: sK[seg][key] = K[k0+key][h*64 + seg*8 ..] ----
        #pragma unroll
        for (int i = 0; i < 2; ++i) {
            const int s = tid + i * 256;
            const int seg = s >> 6, key = s & 63;
            const u16* kp = K + ((size_t)m * 1024 + k0 + key) * 512 + h * 64 + seg * 8;
            *(uint4*)&sK[seg][key][0] = *(const uint4*)kp;
        }
        // ---- stage V tile: sV[ks][d] = Vt[h*64+d][k0 + ks*8 ..] ----
        #pragma unroll
        for (int i = 0; i < 2; ++i) {
            const int s = tid + i * 256;
            const int ks = s >> 6, d = s & 63;
            const u16* vp = Vt + (size_t)m * 524288 + (size_t)(h * 64 + d) * 1024 + k0 + ks * 8;
            *(uint4*)&sV[ks][d][0] = *(const uint4*)vp;
        }
        // ---- stage sv[c][k] = tk[k]@kw1[:,c] ----
        {
            const int c = tid >> 4, k4 = (tid & 15) * 4;
            const float* tkq = tkp + ((size_t)m * 1024 + k0 + k4) * 2;
            float4 ta = *(const float4*)tkq;
            float4 tb = *(const float4*)(tkq + 4);
            const float w0 = kw1[c], w1 = kw1[16 + c];
            float4 vv;
            vv.x = fmaf(ta.x, w0, ta.y * w1);
            vv.y = fmaf(ta.z, w0, ta.w * w1);
            vv.z = fmaf(tb.x, w0, tb.y * w1);
            vv.w = fmaf(tb.z, w0, tb.w * w1);
            *(float4*)&sv[c][k4] = vv;
        }
        __syncthreads();

        // ---- S^T = K·Q^T : s[msub] rows = keys msub*16+quad*4+r, col q=l16 ----
        f4 s[4];
        #pragma unroll
        for (int msub = 0; msub < 4; ++msub) {
            bf8 kf0 = *(const bf8*)&sK[quad][msub * 16 + l16][0];
            bf8 kf1 = *(const bf8*)&sK[4 + quad][msub * 16 + l16][0];
            s[msub] = __builtin_amdgcn_mfma_f32_16x16x32_bf16(kf0, qf[0], (f4)0.f, 0, 0, 0);
            s[msub] = __builtin_amdgcn_mfma_f32_16x16x32_bf16(kf1, qf[1], s[msub], 0, 0, 0);
        }
        // ---- bias: s = s*SCALE + sum_c relu(u[c]-v[c,k])*w2h[c] ----
        #pragma unroll
        for (int msub = 0; msub < 4; ++msub) {
            const int kb = msub * 16 + quad * 4;
            f4 b = (f4)0.f;
            #pragma unroll
            for (int c = 0; c < 16; ++c) {
                float4 vv = *(const float4*)&sv[c][kb];
                const float uc = u[c], wc = w2h[c];
                b[0] = fmaf(fmaxf(uc - vv.x, 0.f), wc, b[0]);
                b[1] = fmaf(fmaxf(uc - vv.y, 0.f), wc, b[1]);
                b[2] = fmaf(fmaxf(uc - vv.z, 0.f), wc, b[2]);
                b[3] = fmaf(fmaxf(uc - vv.w, 0.f), wc, b[3]);
            }
            s[msub] = s[msub] * SCALE + b;
        }
        // ---- online softmax over keys (rows spread over quads) ----
        float mx = -1e30f;
        #pragma unroll
        for (int msub = 0; msub < 4; ++msub) {
            mx = fmaxf(mx, fmaxf(fmaxf(s[msub][0], s[msub][1]),
                                 fmaxf(s[msub][2], s[msub][3])));
        }
        mx = fmaxf(mx, __shfl_xor(mx, 16));
        mx = fmaxf(mx, __shfl_xor(mx, 32));
        const float mnew = fmaxf(mrun, mx);
        const float alpha = __expf(mrun - mnew);
        float ps = 0.f;
        #pragma unroll
        for (int msub = 0; msub < 4; ++msub) {
            #pragma unroll
            for (int r = 0; r < 4; ++r) {
                float p = __expf(s[msub][r] - mnew);
                s[msub][r] = p;
                ps += p;
            }
        }
        ps += __shfl_xor(ps, 16);
        ps += __shfl_xor(ps, 32);
        lrun = lrun * alpha + ps;
        mrun = mnew;
        #pragma unroll
        for (int d = 0; d < 4; ++d) o[d] = o[d] * alpha;
        // ---- write P (bf16) to wave-private sP[q][key] ----
        #pragma unroll
        for (int msub = 0; msub < 4; ++msub) {
            uint2 pw;
            pw.x = pk2(s[msub][0], s[msub][1]);
            pw.y = pk2(s[msub][2], s[msub][3]);
            *(uint2*)&sP[w][l16][msub * 16 + quad * 4] = pw;
        }
        // ---- O^T += Vt·P^T ----
        #pragma unroll
        for (int dsub = 0; dsub < 4; ++dsub) {
            #pragma unroll
            for (int kc2 = 0; kc2 < 2; ++kc2) {
                bf8 vf = *(const bf8*)&sV[kc2 * 4 + quad][dsub * 16 + l16][0];
                bf8 pf = *(const bf8*)&sP[w][l16][kc2 * 32 + quad * 8];
                o[dsub] = __builtin_amdgcn_mfma_f32_16x16x32_bf16(vf, pf, o[dsub], 0, 0, 0);
            }
        }
    }

    // ---- epilogue: O[tok][h*64 + d] = o/l ----
    const float inv = 1.f / lrun;
    #pragma unroll
    for (int dsub = 0; dsub < 4; ++dsub) {
        uint2 pw;
        pw.x = pk2(o[dsub][0] * inv, o[dsub][1] * inv);
        pw.y = pk2(o[dsub][2] * inv, o[dsub][3] * inv);
        *(uint2*)&O[qtok * 512 + h * 64 + dsub * 16 + quad * 4] = pw;
    }
}

// ===========================================================================
extern "C" void kernel_launch(void* const* d_in, const int* in_sizes, int n_in,
                              void* d_out, int out_size, void* d_ws, size_t ws_size,
                              hipStream_t stream) {
    const float* xq    = (const float*)d_in[0];
    const float* xk    = (const float*)d_in[1];
    const float* xv    = (const float*)d_in[2];
    const float* tq    = (const float*)d_in[3];
    const float* tk    = (const float*)d_in[4];
    const float* w_q   = (const float*)d_in[5];
    const float* w_k   = (const float*)d_in[6];
    const float* w_v   = (const float*)d_in[7];
    const float* w_out = (const float*)d_in[8];
    const float* b_out = (const float*)d_in[9];
    const float* kw1   = (const float*)d_in[10];
    const float* kb1   = (const float*)d_in[11];
    const float* kw2   = (const float*)d_in[12];

    const size_t nTok = (size_t)Mb * 1024 * 512;   // 4,194,304 elems
    u16* Q  = (u16*)d_ws;
    u16* Kp = Q + nTok;
    u16* Vt = Kp + nTok;
    u16* O  = Vt + nTok;

    // --- QKV projections (V stored transposed per batch) ---
    GArgs gq;
    gq.A[0] = xq;  gq.A[1] = xk;  gq.A[2] = xv;
    gq.W[0] = w_q; gq.W[1] = w_k; gq.W[2] = w_v;
    gq.C[0] = Q;   gq.C[1] = Kp;  gq.C[2] = Vt;
    gq.bias = nullptr;
    gq.modeT[0] = 0; gq.modeT[1] = 0; gq.modeT[2] = 1;
    gq.outf32 = 0; gq.abf16 = 0;
    gemm_mfma<<<dim3(4, 64, 3), 256, 0, stream>>>(gq);

    // --- fused attention ---
    attn_mfma<<<dim3(16, 8, Mb), 256, 0, stream>>>(Q, Kp, Vt, tq, tk,
                                                   kw1, kb1, kw2, O);

    // --- output projection (f32 + bias) ---
    GArgs go;
    go.A[0] = O;     go.A[1] = O;     go.A[2] = O;
    go.W[0] = w_out; go.W[1] = w_out; go.W[2] = w_out;
    go.C[0] = d_out; go.C[1] = d_out; go.C[2] = d_out;
    go.bias = b_out;
    go.modeT[0] = 0; go.modeT[1] = 0; go.modeT[2] = 0;
    go.outf32 = 1; go.abf16 = 1;
    gemm_mfma<<<dim3(4, 64, 1), 256, 0, stream>>>(go);
}